// Round 6
// baseline (1117.523 us; speedup 1.0000x reference)
//
#include <hip/hip_runtime.h>
#include <stdint.h>

typedef uint16_t u16;
typedef __bf16 bf16x8 __attribute__((ext_vector_type(8)));
typedef float f32x4 __attribute__((ext_vector_type(4)));

#define DEV static __device__ __forceinline__

DEV float bfbits_lo(uint32_t w) { union { uint32_t i; float f; } v; v.i = w << 16; return v.f; }
DEV float bfbits_hi(uint32_t w) { union { uint32_t i; float f; } v; v.i = w & 0xffff0000u; return v.f; }
DEV u16 f2bf(float f) {
    union { float f; uint32_t i; } v; v.f = f;
    uint32_t x = v.i;
    uint32_t r = (x + 0x7fffu + ((x >> 16) & 1u)) >> 16;  // RNE
    return (u16)r;
}

// ------------------------------------------------------------- PREP ----
// One dispatch fusing: 6 weight transposes (blocks 0..4095), F fp32->bf16
// (4096..8191), bias concat (8192..8203), KNN (8204..12299).
__global__ __launch_bounds__(256) void prep_kernel(
    const float* __restrict__ verts, const float* __restrict__ F,
    const float* __restrict__ Wq, const float* __restrict__ Wk,
    const float* __restrict__ Wv, const float* __restrict__ Wo,
    const float* __restrict__ W1, const float* __restrict__ W2,
    const float* __restrict__ bq, const float* __restrict__ bk,
    const float* __restrict__ bv,
    u16* __restrict__ WqkvT, u16* __restrict__ WoT,
    u16* __restrict__ W1T, u16* __restrict__ W2T,
    float* __restrict__ bqkv, u16* __restrict__ Fb, int* __restrict__ nbr) {
    int blk = blockIdx.x;
    int tid = threadIdx.x;
    if (blk < 4096) {
        const float* in; u16* outp; int K, N, t = blk;
        if (t < 512) { in = Wq; outp = WqkvT; K = 512; N = 1024; }
        else if (t < 1024) { t -= 512; in = Wk; outp = WqkvT + 1024 * 512; K = 512; N = 1024; }
        else if (t < 1536) { t -= 1024; in = Wv; outp = WqkvT + 2048 * 512; K = 512; N = 1024; }
        else if (t < 2048) { t -= 1536; in = Wo; outp = WoT; K = 1024; N = 512; }
        else if (t < 3072) { t -= 2048; in = W1; outp = W1T; K = 512; N = 2048; }
        else { t -= 3072; in = W2; outp = W2T; K = 2048; N = 512; }
        int tilesX = N >> 5;
        int bx = t % tilesX, by = t / tilesX;
        int x0 = bx * 32, y0 = by * 32;
        __shared__ float tile[32][33];
        int tx = tid & 31, ty = tid >> 5;  // 32 x 8
#pragma unroll
        for (int r = 0; r < 4; r++) {
            int y = y0 + ty + r * 8;
            tile[ty + r * 8][tx] = in[(size_t)y * N + x0 + tx];
        }
        __syncthreads();
#pragma unroll
        for (int r = 0; r < 4; r++) {
            int nrow = x0 + ty + r * 8;
            outp[(size_t)nrow * K + y0 + tx] = f2bf(tile[tx][ty + r * 8]);
        }
    } else if (blk < 8192) {
        int i = (blk - 4096) * 256 + tid;   // 8 elems each
        const float4* p = (const float4*)F + (size_t)i * 2;
        float4 a = p[0], c = p[1];
        uint32_t w0 = f2bf(a.x) | ((uint32_t)f2bf(a.y) << 16);
        uint32_t w1 = f2bf(a.z) | ((uint32_t)f2bf(a.w) << 16);
        uint32_t w2 = f2bf(c.x) | ((uint32_t)f2bf(c.y) << 16);
        uint32_t w3 = f2bf(c.z) | ((uint32_t)f2bf(c.w) << 16);
        ((uint4*)Fb)[i] = make_uint4(w0, w1, w2, w3);
    } else if (blk < 8204) {
        int i = (blk - 8192) * 256 + tid;
        if (i < 1024) bqkv[i] = bq[i];
        else if (i < 2048) bqkv[i] = bk[i - 1024];
        else if (i < 3072) bqkv[i] = bv[i - 2048];
    } else {
        int wv = (blk - 8204) * 4 + (tid >> 6);
        int l = tid & 63;
        int b = wv >> 10, n = wv & 1023;
        const float* vb = verts + (size_t)b * 1024 * 3;
        float qx = vb[n * 3 + 0], qy = vb[n * 3 + 1], qz = vb[n * 3 + 2];
        float q2 = qx * qx + qy * qy + qz * qz;
        float d[16];
#pragma unroll
        for (int t = 0; t < 16; t++) {
            int p = l + 64 * t;
            float px = vb[p * 3 + 0], py = vb[p * 3 + 1], pz = vb[p * 3 + 2];
            float p2 = px * px + py * py + pz * pz;
            float dot = qx * px + qy * py + qz * pz;
            d[t] = q2 + p2 - 2.f * dot;
        }
        int* outp = nbr + (size_t)wv * 20;
        for (int it = 0; it < 20; it++) {
            float dm = d[0]; int im = 0;
#pragma unroll
            for (int t = 1; t < 16; t++) { if (d[t] < dm) { dm = d[t]; im = t; } }
            int g = im * 64 + l;
#pragma unroll
            for (int off = 32; off >= 1; off >>= 1) {
                float od = __shfl_xor(dm, off);
                int og = __shfl_xor(g, off);
                if (od < dm || (od == dm && og < g)) { dm = od; g = og; }
            }
            int wl = g & 63, wt = g >> 6;
            if (l == wl) {
#pragma unroll
                for (int t = 0; t < 16; t++) if (t == wt) d[t] = 3.4e38f;
            }
            if (l == 0) outp[it] = g;
        }
    }
}

// ---------------------------------------------------------------- GEMM ----
// C[M,N] = A[M,K] * BT[N,K]^T, bf16 in, fp32 accum, MFMA 16x16x32, BK=32,
// 128x128 tile. REGISTER-staged double buffer (no global_load_lds): loads
// go to VGPRs (vmcnt is register-precise, so the waitcnt pass does NOT
// conservatively drain at the ds_read like it does for LDS-DMA), compute
// tile k from LDS, ds_write tile k+1 (its vmcnt wait covers only that
// bank's 4 loads, in flight for ~2 compute phases), raw s_barrier with
// lgkmcnt(0) only. Loads for tile k+2 issue at the top of iter k.
// gridDim.z = split-K (partials). Column-major block remap for L2.
// EPI: 0 bias->bf16 | 1 bias+relu->bf16 | 3 partial->fp32 (Cf/Cf2 by z)
template <int EPI>
__global__ __launch_bounds__(256) void gemm_bt(const u16* __restrict__ A,
                                               const u16* __restrict__ BT,
                                               const float* __restrict__ bias,
                                               u16* __restrict__ Cb,
                                               float* __restrict__ Cf,
                                               float* __restrict__ Cf2,
                                               int M, int N, int Klen,
                                               int lda, int ldb, int Koff) {
    __shared__ __align__(16) u16 As[2][4096];   // 2 bufs x 8KB: [kq][row][8]
    __shared__ __align__(16) u16 Bs[2][4096];
    int tid = threadIdx.x;
    int id = blockIdx.y * gridDim.x + blockIdx.x;
    int by = id % gridDim.y, bx = id / gridDim.y;
    int m0 = by * 128, n0 = bx * 128;
    int kz = blockIdx.z;
    const u16* Ap = A + (size_t)kz * Koff;
    const u16* Bp = BT + (size_t)kz * Koff;
    int w = tid >> 6, l = tid & 63;
    int wr = w >> 1, wc = w & 1, quad = l >> 4, ln = l & 15;
    // staging slots: idx0 = tid -> (kq0, row), idx1 = tid+256 -> (kq0+2, row)
    int kq0 = tid >> 7, rr = tid & 127;
    const u16* arow0 = Ap + (size_t)(m0 + rr) * lda + kq0 * 8;
    const u16* arow1 = arow0 + 16;        // kq + 2 -> +16 elems
    const u16* brow0 = Bp + (size_t)(n0 + rr) * ldb + kq0 * 8;
    const u16* brow1 = brow0 + 16;

    f32x4 acc[4][4];
#pragma unroll
    for (int i = 0; i < 4; i++)
#pragma unroll
        for (int j = 0; j < 4; j++) acc[i][j] = (f32x4){0.f, 0.f, 0.f, 0.f};

    uint4 ra[2][2], rb[2][2];   // [bank][slot]

#define ISSUE(bk, kt) do {                                   \
        ra[bk][0] = *(const uint4*)(arow0 + (kt));           \
        ra[bk][1] = *(const uint4*)(arow1 + (kt));           \
        rb[bk][0] = *(const uint4*)(brow0 + (kt));           \
        rb[bk][1] = *(const uint4*)(brow1 + (kt));           \
    } while (0)
#define DSWRITE(buf, bk) do {                                             \
        *(uint4*)((char*)&As[buf][0] + tid * 16) = ra[bk][0];             \
        *(uint4*)((char*)&As[buf][0] + (tid + 256) * 16) = ra[bk][1];     \
        *(uint4*)((char*)&Bs[buf][0] + tid * 16) = rb[bk][0];             \
        *(uint4*)((char*)&Bs[buf][0] + (tid + 256) * 16) = rb[bk][1];     \
    } while (0)

    int nIter = Klen >> 5;
    ISSUE(0, 0);
    if (nIter > 1) ISSUE(1, 32);
    DSWRITE(0, 0);
    asm volatile("s_waitcnt lgkmcnt(0)" ::: "memory");
    __builtin_amdgcn_s_barrier();
    for (int kt = 0; kt < nIter; kt++) {
        int pb = kt & 1;
        if (kt + 2 < nIter) ISSUE(pb, (kt + 2) * 32);   // bank pb free: tile kt already in LDS
        __builtin_amdgcn_sched_barrier(0);
        const bf16x8* Av = (const bf16x8*)&As[pb][0];
        const bf16x8* Bv = (const bf16x8*)&Bs[pb][0];
        bf16x8 af[4], bfr[4];
#pragma unroll
        for (int i = 0; i < 4; i++) af[i] = Av[quad * 128 + wr * 64 + i * 16 + ln];
#pragma unroll
        for (int j = 0; j < 4; j++) bfr[j] = Bv[quad * 128 + wc * 64 + j * 16 + ln];
#pragma unroll
        for (int i = 0; i < 4; i++)
#pragma unroll
            for (int j = 0; j < 4; j++)
                acc[i][j] = __builtin_amdgcn_mfma_f32_16x16x32_bf16(af[i], bfr[j], acc[i][j], 0, 0, 0);
        __builtin_amdgcn_sched_barrier(0);
        if (kt + 1 < nIter) DSWRITE(pb ^ 1, pb ^ 1);    // waits only bank pb^1's 4 loads
        asm volatile("s_waitcnt lgkmcnt(0)" ::: "memory");
        __builtin_amdgcn_s_barrier();
    }
#undef ISSUE
#undef DSWRITE

    float* Cfz = (EPI == 3) ? (kz ? Cf2 : Cf) : Cf;
    // epilogue: row = m0+wr*64+i*16+quad*4+r, col = n0+wc*64+j*16+ln
#pragma unroll
    for (int i = 0; i < 4; i++) {
        int row_base = m0 + wr * 64 + i * 16 + quad * 4;
#pragma unroll
        for (int j = 0; j < 4; j++) {
            int col = n0 + wc * 64 + j * 16 + ln;
            float bb = (EPI == 3) ? 0.f : bias[col];
#pragma unroll
            for (int r = 0; r < 4; r++) {
                int row = row_base + r;
                size_t o = (size_t)row * N + col;
                float v = acc[i][j][r] + bb;
                if (EPI == 0) Cb[o] = f2bf(v);
                else if (EPI == 1) Cb[o] = f2bf(v > 0.f ? v : 0.f);
                else Cfz[o] = v;
            }
        }
    }
}

// ----------------------------------------------------- sparse attention ----
__global__ __launch_bounds__(256) void attn_kernel(const u16* __restrict__ QKV,
                                                   const int* __restrict__ nbr,
                                                   u16* __restrict__ outA) {
    int tid = threadIdx.x;
    int wv = blockIdx.x * 4 + (tid >> 6);  // b*1024+n
    int l = tid & 63;
    int h = l >> 4, sx = l & 15;
    int bbase = (wv >> 10) << 10;

    int nv = 0;
    if (l < 20) nv = nbr[(size_t)wv * 20 + l];

    const uint32_t* qp = (const uint32_t*)(QKV + (size_t)wv * 3072 + h * 256 + sx * 16);
    uint32_t qw[8];
    *(uint4*)(qw) = *(const uint4*)qp;
    *(uint4*)(qw + 4) = *(const uint4*)(qp + 4);
    float qf[16];
#pragma unroll
    for (int i = 0; i < 8; i++) { qf[2 * i] = bfbits_lo(qw[i]); qf[2 * i + 1] = bfbits_hi(qw[i]); }

    float wj[20];
#pragma unroll
    for (int j = 0; j < 20; j++) {
        int m = __shfl(nv, j);
        const uint32_t* kp = (const uint32_t*)(QKV + (size_t)(bbase + m) * 3072 + 1024 + h * 256 + sx * 16);
        uint32_t kw[8];
        *(uint4*)(kw) = *(const uint4*)kp;
        *(uint4*)(kw + 4) = *(const uint4*)(kp + 4);
        float acc = 0.f;
#pragma unroll
        for (int i = 0; i < 8; i++) {
            acc += qf[2 * i] * bfbits_lo(kw[i]);
            acc += qf[2 * i + 1] * bfbits_hi(kw[i]);
        }
#pragma unroll
        for (int off = 1; off < 16; off <<= 1) acc += __shfl_xor(acc, off);
        wj[j] = acc * 0.0625f;
    }
    float mx = wj[0];
#pragma unroll
    for (int j = 1; j < 20; j++) mx = fmaxf(mx, wj[j]);
    float ssum = 0.f;
#pragma unroll
    for (int j = 0; j < 20; j++) { wj[j] = __expf(wj[j] - mx); ssum += wj[j]; }
    float inv = 1.f / ssum;

    float o[16];
#pragma unroll
    for (int i = 0; i < 16; i++) o[i] = 0.f;
#pragma unroll
    for (int j = 0; j < 20; j++) {
        int m = __shfl(nv, j);
        const uint32_t* vp = (const uint32_t*)(QKV + (size_t)(bbase + m) * 3072 + 2048 + h * 256 + sx * 16);
        uint32_t vw[8];
        *(uint4*)(vw) = *(const uint4*)vp;
        *(uint4*)(vw + 4) = *(const uint4*)(vp + 4);
        float ww = wj[j] * inv;
#pragma unroll
        for (int i = 0; i < 8; i++) {
            o[2 * i] += ww * bfbits_lo(vw[i]);
            o[2 * i + 1] += ww * bfbits_hi(vw[i]);
        }
    }
    uint32_t ow[8];
#pragma unroll
    for (int i = 0; i < 8; i++) ow[i] = f2bf(o[2 * i]) | ((uint32_t)f2bf(o[2 * i + 1]) << 16);
    u16* op = outA + (size_t)wv * 1024 + h * 256 + sx * 16;
    *(uint4*)op = *(uint4*)ow;
    *((uint4*)op + 1) = *(uint4*)(ow + 4);
}

// ------------------------------------------------- LN over split-K sum ----
// LN(P0 + P1 + res + biasv) -> Yf fp32 (+ Yb bf16 if WB)
template <int WB>
__global__ __launch_bounds__(256) void ln12p_kernel(const float* __restrict__ P0,
                                                    const float* __restrict__ P1,
                                                    const float* __restrict__ res,
                                                    const float* __restrict__ biasv,
                                                    const float* __restrict__ g,
                                                    const float* __restrict__ bparm,
                                                    float* __restrict__ Yf,
                                                    u16* __restrict__ Yb) {
    int tid = threadIdx.x;
    int row = blockIdx.x * 4 + (tid >> 6);
    int l = tid & 63;
    size_t base = (size_t)row * 512;
    const float4* p0 = (const float4*)(P0 + base) + l * 2;
    const float4* p1 = (const float4*)(P1 + base) + l * 2;
    const float4* rr = (const float4*)(res + base) + l * 2;
    const float4* bv = (const float4*)biasv + l * 2;
    float xs[8];
#pragma unroll
    for (int h = 0; h < 2; h++) {
        float4 a = p0[h], b = p1[h], c = rr[h], d = bv[h];
        xs[4 * h + 0] = a.x + b.x + c.x + d.x;
        xs[4 * h + 1] = a.y + b.y + c.y + d.y;
        xs[4 * h + 2] = a.z + b.z + c.z + d.z;
        xs[4 * h + 3] = a.w + b.w + c.w + d.w;
    }
    float s = 0.f;
#pragma unroll
    for (int i = 0; i < 8; i++) s += xs[i];
#pragma unroll
    for (int off = 32; off >= 1; off >>= 1) s += __shfl_xor(s, off);
    float mu = s * (1.f / 512.f);
    float q = 0.f;
#pragma unroll
    for (int i = 0; i < 8; i++) { float dd = xs[i] - mu; q += dd * dd; }
#pragma unroll
    for (int off = 32; off >= 1; off >>= 1) q += __shfl_xor(q, off);
    float var = q * (1.f / 512.f);
    float rs = rsqrtf(var + 1e-5f);
    const float4* gp = (const float4*)g + l * 2;
    const float4* bp = (const float4*)bparm + l * 2;
    float4 g0 = gp[0], g1 = gp[1], b0 = bp[0], b1 = bp[1];
    float gg[8] = {g0.x, g0.y, g0.z, g0.w, g1.x, g1.y, g1.z, g1.w};
    float bbv[8] = {b0.x, b0.y, b0.z, b0.w, b1.x, b1.y, b1.z, b1.w};
    float y[8];
#pragma unroll
    for (int i = 0; i < 8; i++) y[i] = (xs[i] - mu) * rs * gg[i] + bbv[i];
    float4* yo = (float4*)(Yf + base) + l * 2;
    yo[0] = make_float4(y[0], y[1], y[2], y[3]);
    yo[1] = make_float4(y[4], y[5], y[6], y[7]);
    if (WB) {
        uint32_t w0 = f2bf(y[0]) | ((uint32_t)f2bf(y[1]) << 16);
        uint32_t w1 = f2bf(y[2]) | ((uint32_t)f2bf(y[3]) << 16);
        uint32_t w2 = f2bf(y[4]) | ((uint32_t)f2bf(y[5]) << 16);
        uint32_t w3 = f2bf(y[6]) | ((uint32_t)f2bf(y[7]) << 16);
        *(uint4*)(Yb + base + l * 8) = make_uint4(w0, w1, w2, w3);
    }
}

// ------------------------------------------------------------ launcher ----
extern "C" void kernel_launch(void* const* d_in, const int* in_sizes, int n_in,
                              void* d_out, int out_size, void* d_ws, size_t ws_size,
                              hipStream_t stream) {
    const float* verts = (const float*)d_in[0];
    const float* F = (const float*)d_in[1];
    const float* Wq = (const float*)d_in[2];
    const float* bq = (const float*)d_in[3];
    const float* Wk = (const float*)d_in[4];
    const float* bk = (const float*)d_in[5];
    const float* Wv = (const float*)d_in[6];
    const float* bv = (const float*)d_in[7];
    const float* Wo = (const float*)d_in[8];
    const float* bo = (const float*)d_in[9];
    const float* ln1g = (const float*)d_in[10];
    const float* ln1b = (const float*)d_in[11];
    const float* W1 = (const float*)d_in[12];
    const float* b1 = (const float*)d_in[13];
    const float* W2 = (const float*)d_in[14];
    const float* b2 = (const float*)d_in[15];
    const float* ln2g = (const float*)d_in[16];
    const float* ln2b = (const float*)d_in[17];
    float* out = (float*)d_out;

    char* ws = (char*)d_ws;
    // arena (lifetime-overlapped), ~177.5 MB:
    u16* QKV = (u16*)(ws);                         // [0, 96MB)  G1 -> attn
    float* Q0 = (float*)(ws);                      // [0, 32MB)  G2 partial 0 -> LN1
    float* Q1 = (float*)(ws + 33554432);           // [32, 64MB) G2 partial 1 -> LN1
    u16* Hb = (u16*)(ws);                          // [0, 64MB)  G3 -> G4
    float* P1 = (float*)(ws + 67108864);           // [64, 96MB) G4 partial 1 -> LN2
    u16* ATT = (u16*)(ws + 100663296);             // [96, 128MB) attn -> G2
    u16* xb = ATT;                                 //   reuse: LN1 -> G3
    float* P0 = (float*)(ws + 100663296);          //   reuse: G4 partial 0 -> LN2
    u16* Fb = (u16*)(ws + 134217728);              // [128, 144.8MB) prep -> G1
    float* X32 = (float*)(ws + 134217728);         //   reuse: LN1 -> LN2 (33.5MB)
    char* wsw = ws + 167772160;
    u16* WqkvT = (u16*)(wsw);                      // 3,145,728
    u16* WoT = (u16*)(wsw + 3145728);              // 1,048,576
    u16* W1T = (u16*)(wsw + 4194304);              // 2,097,152
    u16* W2T = (u16*)(wsw + 6291456);              // 2,097,152
    float* bqkv = (float*)(wsw + 8388608);         // 16,384 (padded)
    int* nbr = (int*)(wsw + 8404992);              // 1,310,720

    // PREP (one dispatch): transposes + convert + bias + KNN
    prep_kernel<<<12300, 256, 0, stream>>>(verts, F, Wq, Wk, Wv, Wo, W1, W2,
                                           bq, bk, bv, WqkvT, WoT, W1T, W2T,
                                           bqkv, Fb, nbr);
    // G1: QKV = Fb @ Wqkv + bias -> bf16 [16384, 3072]
    gemm_bt<0><<<dim3(24, 128, 1), 256, 0, stream>>>(Fb, WqkvT, bqkv, QKV, nullptr, nullptr,
                                                     16384, 3072, 512, 512, 512, 0);
    // sparse attention -> ATT bf16 [16384, 1024]
    attn_kernel<<<4096, 256, 0, stream>>>(QKV, nbr, ATT);
    // G2 split-K x2 (one dispatch): Q0/Q1 = ATT @ Wo (partials) [16384, 512]
    gemm_bt<3><<<dim3(4, 128, 2), 256, 0, stream>>>(ATT, WoT, nullptr, nullptr, Q0, Q1,
                                                    16384, 512, 512, 1024, 1024, 512);
    // LN1: LN(Q0+Q1+bo+F) -> X32 fp32 + xb bf16
    ln12p_kernel<1><<<4096, 256, 0, stream>>>(Q0, Q1, F, bo, ln1g, ln1b, X32, xb);
    // G3: Hb = relu(xb @ W1 + b1) -> bf16 [16384, 2048]
    gemm_bt<1><<<dim3(16, 128, 1), 256, 0, stream>>>(xb, W1T, b1, Hb, nullptr, nullptr,
                                                     16384, 2048, 512, 512, 512, 0);
    // G4 split-K x2 (one dispatch): P0/P1 = Hb @ W2 (partials) [16384, 512]
    gemm_bt<3><<<dim3(4, 128, 2), 256, 0, stream>>>(Hb, W2T, nullptr, nullptr, P0, P1,
                                                    16384, 512, 1024, 2048, 2048, 1024);
    // LN2: LN(P0+P1+b2+X32) -> out
    ln12p_kernel<0><<<4096, 256, 0, stream>>>(P0, P1, X32, b2, ln2g, ln2b, out, nullptr);
}

// Round 7
// 632.421 us; speedup vs baseline: 1.7671x; 1.7671x over previous
//
#include <hip/hip_runtime.h>
#include <stdint.h>

typedef uint16_t u16;
typedef __bf16 bf16x8 __attribute__((ext_vector_type(8)));
typedef float f32x4 __attribute__((ext_vector_type(4)));

#define DEV static __device__ __forceinline__

DEV float bfbits_lo(uint32_t w) { union { uint32_t i; float f; } v; v.i = w << 16; return v.f; }
DEV float bfbits_hi(uint32_t w) { union { uint32_t i; float f; } v; v.i = w & 0xffff0000u; return v.f; }
DEV u16 f2bf(float f) {
    union { float f; uint32_t i; } v; v.f = f;
    uint32_t x = v.i;
    uint32_t r = (x + 0x7fffu + ((x >> 16) & 1u)) >> 16;  // RNE
    return (u16)r;
}

// ------------------------------------------------------------- PREP ----
// One dispatch fusing: 6 weight transposes (blocks 0..4095), F fp32->bf16
// (4096..8191), bias concat (8192..8203), KNN (8204..12299).
__global__ __launch_bounds__(256) void prep_kernel(
    const float* __restrict__ verts, const float* __restrict__ F,
    const float* __restrict__ Wq, const float* __restrict__ Wk,
    const float* __restrict__ Wv, const float* __restrict__ Wo,
    const float* __restrict__ W1, const float* __restrict__ W2,
    const float* __restrict__ bq, const float* __restrict__ bk,
    const float* __restrict__ bv,
    u16* __restrict__ WqkvT, u16* __restrict__ WoT,
    u16* __restrict__ W1T, u16* __restrict__ W2T,
    float* __restrict__ bqkv, u16* __restrict__ Fb, int* __restrict__ nbr) {
    int blk = blockIdx.x;
    int tid = threadIdx.x;
    if (blk < 4096) {
        const float* in; u16* outp; int K, N, t = blk;
        if (t < 512) { in = Wq; outp = WqkvT; K = 512; N = 1024; }
        else if (t < 1024) { t -= 512; in = Wk; outp = WqkvT + 1024 * 512; K = 512; N = 1024; }
        else if (t < 1536) { t -= 1024; in = Wv; outp = WqkvT + 2048 * 512; K = 512; N = 1024; }
        else if (t < 2048) { t -= 1536; in = Wo; outp = WoT; K = 1024; N = 512; }
        else if (t < 3072) { t -= 2048; in = W1; outp = W1T; K = 512; N = 2048; }
        else { t -= 3072; in = W2; outp = W2T; K = 2048; N = 512; }
        int tilesX = N >> 5;
        int bx = t % tilesX, by = t / tilesX;
        int x0 = bx * 32, y0 = by * 32;
        __shared__ float tile[32][33];
        int tx = tid & 31, ty = tid >> 5;  // 32 x 8
#pragma unroll
        for (int r = 0; r < 4; r++) {
            int y = y0 + ty + r * 8;
            tile[ty + r * 8][tx] = in[(size_t)y * N + x0 + tx];
        }
        __syncthreads();
#pragma unroll
        for (int r = 0; r < 4; r++) {
            int nrow = x0 + ty + r * 8;
            outp[(size_t)nrow * K + y0 + tx] = f2bf(tile[tx][ty + r * 8]);
        }
    } else if (blk < 8192) {
        int i = (blk - 4096) * 256 + tid;   // 8 elems each
        const float4* p = (const float4*)F + (size_t)i * 2;
        float4 a = p[0], c = p[1];
        uint32_t w0 = f2bf(a.x) | ((uint32_t)f2bf(a.y) << 16);
        uint32_t w1 = f2bf(a.z) | ((uint32_t)f2bf(a.w) << 16);
        uint32_t w2 = f2bf(c.x) | ((uint32_t)f2bf(c.y) << 16);
        uint32_t w3 = f2bf(c.z) | ((uint32_t)f2bf(c.w) << 16);
        ((uint4*)Fb)[i] = make_uint4(w0, w1, w2, w3);
    } else if (blk < 8204) {
        int i = (blk - 8192) * 256 + tid;
        if (i < 1024) bqkv[i] = bq[i];
        else if (i < 2048) bqkv[i] = bk[i - 1024];
        else if (i < 3072) bqkv[i] = bv[i - 2048];
    } else {
        int wv = (blk - 8204) * 4 + (tid >> 6);
        int l = tid & 63;
        int b = wv >> 10, n = wv & 1023;
        const float* vb = verts + (size_t)b * 1024 * 3;
        float qx = vb[n * 3 + 0], qy = vb[n * 3 + 1], qz = vb[n * 3 + 2];
        float q2 = qx * qx + qy * qy + qz * qz;
        float d[16];
#pragma unroll
        for (int t = 0; t < 16; t++) {
            int p = l + 64 * t;
            float px = vb[p * 3 + 0], py = vb[p * 3 + 1], pz = vb[p * 3 + 2];
            float p2 = px * px + py * py + pz * pz;
            float dot = qx * px + qy * py + qz * pz;
            d[t] = q2 + p2 - 2.f * dot;
        }
        int* outp = nbr + (size_t)wv * 20;
        for (int it = 0; it < 20; it++) {
            float dm = d[0]; int im = 0;
#pragma unroll
            for (int t = 1; t < 16; t++) { if (d[t] < dm) { dm = d[t]; im = t; } }
            int g = im * 64 + l;
#pragma unroll
            for (int off = 32; off >= 1; off >>= 1) {
                float od = __shfl_xor(dm, off);
                int og = __shfl_xor(g, off);
                if (od < dm || (od == dm && og < g)) { dm = od; g = og; }
            }
            int wl = g & 63, wt = g >> 6;
            if (l == wl) {
#pragma unroll
                for (int t = 0; t < 16; t++) if (t == wt) d[t] = 3.4e38f;
            }
            if (l == 0) outp[it] = g;
        }
    }
}

// ---------------------------------------------------------------- GEMM ----
// C[M,N] = A[M,K] * BT[N,K]^T, bf16 in, fp32 accum, MFMA 16x16x32, BK=32,
// 128x128 tile. Register-staged double buffer, K-loop unrolled x2 so every
// bank<->buffer binding is a compile-time constant (R6's runtime-indexed
// staging arrays spilled to scratch: WRITE_SIZE 98->809MB). Per 2 tiles:
//   issue bank0<-k+2 | compute buf0 | ds_write buf1<-bank1 (vmcnt wait is
//   register-precise, loads are a full body old) | lgkm+barrier |
//   issue bank1<-k+3 | compute buf1 | ds_write buf0<-bank0 | lgkm+barrier
// No vmcnt(0) drain anywhere. nIter even (16/32) -> no tail tile.
// gridDim.z = split-K (partials). Column-major block remap for L2.
// EPI: 0 bias->bf16 | 1 bias+relu->bf16 | 3 partial->fp32 (Cf/Cf2 by z)
template <int EPI>
__global__ __launch_bounds__(256) void gemm_bt(const u16* __restrict__ A,
                                               const u16* __restrict__ BT,
                                               const float* __restrict__ bias,
                                               u16* __restrict__ Cb,
                                               float* __restrict__ Cf,
                                               float* __restrict__ Cf2,
                                               int M, int N, int Klen,
                                               int lda, int ldb, int Koff) {
    __shared__ __align__(16) u16 As0[4096], As1[4096];   // 8KB each: [kq][row][8]
    __shared__ __align__(16) u16 Bs0[4096], Bs1[4096];
    int tid = threadIdx.x;
    int id = blockIdx.y * gridDim.x + blockIdx.x;
    int by = id % gridDim.y, bx = id / gridDim.y;
    int m0 = by * 128, n0 = bx * 128;
    int kz = blockIdx.z;
    const u16* Ap = A + (size_t)kz * Koff;
    const u16* Bp = BT + (size_t)kz * Koff;
    int w = tid >> 6, l = tid & 63;
    int wr = w >> 1, wc = w & 1, quad = l >> 4, ln = l & 15;
    // staging: slot0 = tid -> (kq0, row), slot1 = tid+256 -> (kq0+2, row)
    int kq0 = tid >> 7, rr = tid & 127;
    const u16* arow0 = Ap + (size_t)(m0 + rr) * lda + kq0 * 8;
    const u16* arow1 = arow0 + 16;
    const u16* brow0 = Bp + (size_t)(n0 + rr) * ldb + kq0 * 8;
    const u16* brow1 = brow0 + 16;

    f32x4 acc[4][4];
#pragma unroll
    for (int i = 0; i < 4; i++)
#pragma unroll
        for (int j = 0; j < 4; j++) acc[i][j] = (f32x4){0.f, 0.f, 0.f, 0.f};

    uint4 a00, a01, b00, b01;   // bank 0 (even tiles -> buf0)
    uint4 a10, a11, b10, b11;   // bank 1 (odd tiles  -> buf1)

#define ISSUE0(ko) do { a00 = *(const uint4*)(arow0 + (ko)); a01 = *(const uint4*)(arow1 + (ko)); \
                        b00 = *(const uint4*)(brow0 + (ko)); b01 = *(const uint4*)(brow1 + (ko)); } while (0)
#define ISSUE1(ko) do { a10 = *(const uint4*)(arow0 + (ko)); a11 = *(const uint4*)(arow1 + (ko)); \
                        b10 = *(const uint4*)(brow0 + (ko)); b11 = *(const uint4*)(brow1 + (ko)); } while (0)
#define WRITE0() do { *(uint4*)((char*)As0 + tid * 16) = a00; *(uint4*)((char*)As0 + (tid + 256) * 16) = a01; \
                      *(uint4*)((char*)Bs0 + tid * 16) = b00; *(uint4*)((char*)Bs0 + (tid + 256) * 16) = b01; } while (0)
#define WRITE1() do { *(uint4*)((char*)As1 + tid * 16) = a10; *(uint4*)((char*)As1 + (tid + 256) * 16) = a11; \
                      *(uint4*)((char*)Bs1 + tid * 16) = b10; *(uint4*)((char*)Bs1 + (tid + 256) * 16) = b11; } while (0)
#define COMPUTE(Asb, Bsb) do {                                                            \
        const bf16x8* Av = (const bf16x8*)(Asb);                                          \
        const bf16x8* Bv = (const bf16x8*)(Bsb);                                          \
        bf16x8 af[4], bfr[4];                                                             \
        _Pragma("unroll")                                                                 \
        for (int i = 0; i < 4; i++) af[i] = Av[quad * 128 + wr * 64 + i * 16 + ln];       \
        _Pragma("unroll")                                                                 \
        for (int j = 0; j < 4; j++) bfr[j] = Bv[quad * 128 + wc * 64 + j * 16 + ln];      \
        _Pragma("unroll")                                                                 \
        for (int i = 0; i < 4; i++)                                                       \
            _Pragma("unroll")                                                             \
            for (int j = 0; j < 4; j++)                                                   \
                acc[i][j] = __builtin_amdgcn_mfma_f32_16x16x32_bf16(af[i], bfr[j], acc[i][j], 0, 0, 0); \
    } while (0)
#define LGKM_BARRIER() do { asm volatile("s_waitcnt lgkmcnt(0)" ::: "memory"); \
                            __builtin_amdgcn_s_barrier(); } while (0)

    int nIter = Klen >> 5;   // even, >= 4 for all shapes used
    ISSUE0(0);
    ISSUE1(32);
    WRITE0();
    LGKM_BARRIER();
    for (int kt = 0; kt < nIter; kt += 2) {
        if (kt + 2 < nIter) ISSUE0((kt + 2) * 32);
        COMPUTE(As0, Bs0);                 // tile kt
        WRITE1();                          // tile kt+1 (bank1 loads ~1 body old)
        LGKM_BARRIER();
        if (kt + 3 < nIter) ISSUE1((kt + 3) * 32);
        COMPUTE(As1, Bs1);                 // tile kt+1
        if (kt + 2 < nIter) {
            WRITE0();                      // tile kt+2 (bank0 loads ~1 body old)
            LGKM_BARRIER();
        }
    }
#undef ISSUE0
#undef ISSUE1
#undef WRITE0
#undef WRITE1
#undef COMPUTE
#undef LGKM_BARRIER

    float* Cfz = (EPI == 3) ? (kz ? Cf2 : Cf) : Cf;
    // epilogue: row = m0+wr*64+i*16+quad*4+r, col = n0+wc*64+j*16+ln
#pragma unroll
    for (int i = 0; i < 4; i++) {
        int row_base = m0 + wr * 64 + i * 16 + quad * 4;
#pragma unroll
        for (int j = 0; j < 4; j++) {
            int col = n0 + wc * 64 + j * 16 + ln;
            float bb = (EPI == 3) ? 0.f : bias[col];
#pragma unroll
            for (int r = 0; r < 4; r++) {
                int row = row_base + r;
                size_t o = (size_t)row * N + col;
                float v = acc[i][j][r] + bb;
                if (EPI == 0) Cb[o] = f2bf(v);
                else if (EPI == 1) Cb[o] = f2bf(v > 0.f ? v : 0.f);
                else Cfz[o] = v;
            }
        }
    }
}

// ----------------------------------------------------- sparse attention ----
__global__ __launch_bounds__(256) void attn_kernel(const u16* __restrict__ QKV,
                                                   const int* __restrict__ nbr,
                                                   u16* __restrict__ outA) {
    int tid = threadIdx.x;
    int wv = blockIdx.x * 4 + (tid >> 6);  // b*1024+n
    int l = tid & 63;
    int h = l >> 4, sx = l & 15;
    int bbase = (wv >> 10) << 10;

    int nv = 0;
    if (l < 20) nv = nbr[(size_t)wv * 20 + l];

    const uint32_t* qp = (const uint32_t*)(QKV + (size_t)wv * 3072 + h * 256 + sx * 16);
    uint32_t qw[8];
    *(uint4*)(qw) = *(const uint4*)qp;
    *(uint4*)(qw + 4) = *(const uint4*)(qp + 4);
    float qf[16];
#pragma unroll
    for (int i = 0; i < 8; i++) { qf[2 * i] = bfbits_lo(qw[i]); qf[2 * i + 1] = bfbits_hi(qw[i]); }

    float wj[20];
#pragma unroll
    for (int j = 0; j < 20; j++) {
        int m = __shfl(nv, j);
        const uint32_t* kp = (const uint32_t*)(QKV + (size_t)(bbase + m) * 3072 + 1024 + h * 256 + sx * 16);
        uint32_t kw[8];
        *(uint4*)(kw) = *(const uint4*)kp;
        *(uint4*)(kw + 4) = *(const uint4*)(kp + 4);
        float acc = 0.f;
#pragma unroll
        for (int i = 0; i < 8; i++) {
            acc += qf[2 * i] * bfbits_lo(kw[i]);
            acc += qf[2 * i + 1] * bfbits_hi(kw[i]);
        }
#pragma unroll
        for (int off = 1; off < 16; off <<= 1) acc += __shfl_xor(acc, off);
        wj[j] = acc * 0.0625f;
    }
    float mx = wj[0];
#pragma unroll
    for (int j = 1; j < 20; j++) mx = fmaxf(mx, wj[j]);
    float ssum = 0.f;
#pragma unroll
    for (int j = 0; j < 20; j++) { wj[j] = __expf(wj[j] - mx); ssum += wj[j]; }
    float inv = 1.f / ssum;

    float o[16];
#pragma unroll
    for (int i = 0; i < 16; i++) o[i] = 0.f;
#pragma unroll
    for (int j = 0; j < 20; j++) {
        int m = __shfl(nv, j);
        const uint32_t* vp = (const uint32_t*)(QKV + (size_t)(bbase + m) * 3072 + 2048 + h * 256 + sx * 16);
        uint32_t vw[8];
        *(uint4*)(vw) = *(const uint4*)vp;
        *(uint4*)(vw + 4) = *(const uint4*)(vp + 4);
        float ww = wj[j] * inv;
#pragma unroll
        for (int i = 0; i < 8; i++) {
            o[2 * i] += ww * bfbits_lo(vw[i]);
            o[2 * i + 1] += ww * bfbits_hi(vw[i]);
        }
    }
    uint32_t ow[8];
#pragma unroll
    for (int i = 0; i < 8; i++) ow[i] = f2bf(o[2 * i]) | ((uint32_t)f2bf(o[2 * i + 1]) << 16);
    u16* op = outA + (size_t)wv * 1024 + h * 256 + sx * 16;
    *(uint4*)op = *(uint4*)ow;
    *((uint4*)op + 1) = *(uint4*)(ow + 4);
}

// ------------------------------------------------- LN over split-K sum ----
// LN(P0 + P1 + res + biasv) -> Yf fp32 (+ Yb bf16 if WB)
template <int WB>
__global__ __launch_bounds__(256) void ln12p_kernel(const float* __restrict__ P0,
                                                    const float* __restrict__ P1,
                                                    const float* __restrict__ res,
                                                    const float* __restrict__ biasv,
                                                    const float* __restrict__ g,
                                                    const float* __restrict__ bparm,
                                                    float* __restrict__ Yf,
                                                    u16* __restrict__ Yb) {
    int tid = threadIdx.x;
    int row = blockIdx.x * 4 + (tid >> 6);
    int l = tid & 63;
    size_t base = (size_t)row * 512;
    const float4* p0 = (const float4*)(P0 + base) + l * 2;
    const float4* p1 = (const float4*)(P1 + base) + l * 2;
    const float4* rr = (const float4*)(res + base) + l * 2;
    const float4* bv = (const float4*)biasv + l * 2;
    float xs[8];
#pragma unroll
    for (int h = 0; h < 2; h++) {
        float4 a = p0[h], b = p1[h], c = rr[h], d = bv[h];
        xs[4 * h + 0] = a.x + b.x + c.x + d.x;
        xs[4 * h + 1] = a.y + b.y + c.y + d.y;
        xs[4 * h + 2] = a.z + b.z + c.z + d.z;
        xs[4 * h + 3] = a.w + b.w + c.w + d.w;
    }
    float s = 0.f;
#pragma unroll
    for (int i = 0; i < 8; i++) s += xs[i];
#pragma unroll
    for (int off = 32; off >= 1; off >>= 1) s += __shfl_xor(s, off);
    float mu = s * (1.f / 512.f);
    float q = 0.f;
#pragma unroll
    for (int i = 0; i < 8; i++) { float dd = xs[i] - mu; q += dd * dd; }
#pragma unroll
    for (int off = 32; off >= 1; off >>= 1) q += __shfl_xor(q, off);
    float var = q * (1.f / 512.f);
    float rs = rsqrtf(var + 1e-5f);
    const float4* gp = (const float4*)g + l * 2;
    const float4* bp = (const float4*)bparm + l * 2;
    float4 g0 = gp[0], g1 = gp[1], b0 = bp[0], b1 = bp[1];
    float gg[8] = {g0.x, g0.y, g0.z, g0.w, g1.x, g1.y, g1.z, g1.w};
    float bbv[8] = {b0.x, b0.y, b0.z, b0.w, b1.x, b1.y, b1.z, b1.w};
    float y[8];
#pragma unroll
    for (int i = 0; i < 8; i++) y[i] = (xs[i] - mu) * rs * gg[i] + bbv[i];
    float4* yo = (float4*)(Yf + base) + l * 2;
    yo[0] = make_float4(y[0], y[1], y[2], y[3]);
    yo[1] = make_float4(y[4], y[5], y[6], y[7]);
    if (WB) {
        uint32_t w0 = f2bf(y[0]) | ((uint32_t)f2bf(y[1]) << 16);
        uint32_t w1 = f2bf(y[2]) | ((uint32_t)f2bf(y[3]) << 16);
        uint32_t w2 = f2bf(y[4]) | ((uint32_t)f2bf(y[5]) << 16);
        uint32_t w3 = f2bf(y[6]) | ((uint32_t)f2bf(y[7]) << 16);
        *(uint4*)(Yb + base + l * 8) = make_uint4(w0, w1, w2, w3);
    }
}

// ------------------------------------------------------------ launcher ----
extern "C" void kernel_launch(void* const* d_in, const int* in_sizes, int n_in,
                              void* d_out, int out_size, void* d_ws, size_t ws_size,
                              hipStream_t stream) {
    const float* verts = (const float*)d_in[0];
    const float* F = (const float*)d_in[1];
    const float* Wq = (const float*)d_in[2];
    const float* bq = (const float*)d_in[3];
    const float* Wk = (const float*)d_in[4];
    const float* bk = (const float*)d_in[5];
    const float* Wv = (const float*)d_in[6];
    const float* bv = (const float*)d_in[7];
    const float* Wo = (const float*)d_in[8];
    const float* bo = (const float*)d_in[9];
    const float* ln1g = (const float*)d_in[10];
    const float* ln1b = (const float*)d_in[11];
    const float* W1 = (const float*)d_in[12];
    const float* b1 = (const float*)d_in[13];
    const float* W2 = (const float*)d_in[14];
    const float* b2 = (const float*)d_in[15];
    const float* ln2g = (const float*)d_in[16];
    const float* ln2b = (const float*)d_in[17];
    float* out = (float*)d_out;

    char* ws = (char*)d_ws;
    // arena (lifetime-overlapped), ~177.5 MB:
    u16* QKV = (u16*)(ws);                         // [0, 96MB)  G1 -> attn
    float* Q0 = (float*)(ws);                      // [0, 32MB)  G2 partial 0 -> LN1
    float* Q1 = (float*)(ws + 33554432);           // [32, 64MB) G2 partial 1 -> LN1
    u16* Hb = (u16*)(ws);                          // [0, 64MB)  G3 -> G4
    float* P1 = (float*)(ws + 67108864);           // [64, 96MB) G4 partial 1 -> LN2
    u16* ATT = (u16*)(ws + 100663296);             // [96, 128MB) attn -> G2
    u16* xb = ATT;                                 //   reuse: LN1 -> G3
    float* P0 = (float*)(ws + 100663296);          //   reuse: G4 partial 0 -> LN2
    u16* Fb = (u16*)(ws + 134217728);              // [128, 144.8MB) prep -> G1
    float* X32 = (float*)(ws + 134217728);         //   reuse: LN1 -> LN2 (33.5MB)
    char* wsw = ws + 167772160;
    u16* WqkvT = (u16*)(wsw);                      // 3,145,728
    u16* WoT = (u16*)(wsw + 3145728);              // 1,048,576
    u16* W1T = (u16*)(wsw + 4194304);              // 2,097,152
    u16* W2T = (u16*)(wsw + 6291456);              // 2,097,152
    float* bqkv = (float*)(wsw + 8388608);         // 16,384 (padded)
    int* nbr = (int*)(wsw + 8404992);              // 1,310,720

    // PREP (one dispatch): transposes + convert + bias + KNN
    prep_kernel<<<12300, 256, 0, stream>>>(verts, F, Wq, Wk, Wv, Wo, W1, W2,
                                           bq, bk, bv, WqkvT, WoT, W1T, W2T,
                                           bqkv, Fb, nbr);
    // G1: QKV = Fb @ Wqkv + bias -> bf16 [16384, 3072]
    gemm_bt<0><<<dim3(24, 128, 1), 256, 0, stream>>>(Fb, WqkvT, bqkv, QKV, nullptr, nullptr,
                                                     16384, 3072, 512, 512, 512, 0);
    // sparse attention -> ATT bf16 [16384, 1024]
    attn_kernel<<<4096, 256, 0, stream>>>(QKV, nbr, ATT);
    // G2 split-K x2 (one dispatch): Q0/Q1 = ATT @ Wo (partials) [16384, 512]
    gemm_bt<3><<<dim3(4, 128, 2), 256, 0, stream>>>(ATT, WoT, nullptr, nullptr, Q0, Q1,
                                                    16384, 512, 512, 1024, 1024, 512);
    // LN1: LN(Q0+Q1+bo+F) -> X32 fp32 + xb bf16
    ln12p_kernel<1><<<4096, 256, 0, stream>>>(Q0, Q1, F, bo, ln1g, ln1b, X32, xb);
    // G3: Hb = relu(xb @ W1 + b1) -> bf16 [16384, 2048]
    gemm_bt<1><<<dim3(16, 128, 1), 256, 0, stream>>>(xb, W1T, b1, Hb, nullptr, nullptr,
                                                     16384, 2048, 512, 512, 512, 0);
    // G4 split-K x2 (one dispatch): P0/P1 = Hb @ W2 (partials) [16384, 512]
    gemm_bt<3><<<dim3(4, 128, 2), 256, 0, stream>>>(Hb, W2T, nullptr, nullptr, P0, P1,
                                                    16384, 512, 1024, 2048, 2048, 1024);
    // LN2: LN(P0+P1+b2+X32) -> out
    ln12p_kernel<0><<<4096, 256, 0, stream>>>(P0, P1, X32, b2, ln2g, ln2b, out, nullptr);
}

// Round 8
// 560.585 us; speedup vs baseline: 1.9935x; 1.1281x over previous
//
#include <hip/hip_runtime.h>
#include <stdint.h>

typedef uint16_t u16;
typedef __bf16 bf16x8 __attribute__((ext_vector_type(8)));
typedef float f32x4 __attribute__((ext_vector_type(4)));

#define DEV static __device__ __forceinline__

DEV float bfbits_lo(uint32_t w) { union { uint32_t i; float f; } v; v.i = w << 16; return v.f; }
DEV float bfbits_hi(uint32_t w) { union { uint32_t i; float f; } v; v.i = w & 0xffff0000u; return v.f; }
DEV u16 f2bf(float f) {
    union { float f; uint32_t i; } v; v.f = f;
    uint32_t x = v.i;
    uint32_t r = (x + 0x7fffu + ((x >> 16) & 1u)) >> 16;  // RNE
    return (u16)r;
}

// Packed operand layout ("panels"): element (row, k) of a [R x K] matrix
// lives at u16 index ((k>>3)*R + row)*8 + (k&7)  == uint4 slot (k>>3)*R + row.
// A wave staging 64 consecutive rows of one panel reads 1KB CONTIGUOUS
// (vs the old row-major gather: 64 lanes x 1KB stride = 64 txns/instr).

// ------------------------------------------------------------- PREP ----
// blocks 0..4095: weight transpose+pack; 4096..8191: F pack; 8192..8203:
// bias concat; 8204..12299: KNN.
__global__ __launch_bounds__(256) void prep_kernel(
    const float* __restrict__ verts, const float* __restrict__ F,
    const float* __restrict__ Wq, const float* __restrict__ Wk,
    const float* __restrict__ Wv, const float* __restrict__ Wo,
    const float* __restrict__ W1, const float* __restrict__ W2,
    const float* __restrict__ bq, const float* __restrict__ bk,
    const float* __restrict__ bv,
    u16* __restrict__ WqkvT, u16* __restrict__ WoT,
    u16* __restrict__ W1T, u16* __restrict__ W2T,
    float* __restrict__ bqkv, u16* __restrict__ Fb, int* __restrict__ nbr) {
    int blk = blockIdx.x;
    int tid = threadIdx.x;
    if (blk < 4096) {
        // transpose W[K][Nsrc] -> packed BT panels [(k>>3)*NB + noff + n][k&7]
        const float* in; u16* outp; int K, Nsrc, NB, noff, t = blk;
        if (t < 512) { in = Wq; outp = WqkvT; K = 512; Nsrc = 1024; NB = 3072; noff = 0; }
        else if (t < 1024) { t -= 512; in = Wk; outp = WqkvT; K = 512; Nsrc = 1024; NB = 3072; noff = 1024; }
        else if (t < 1536) { t -= 1024; in = Wv; outp = WqkvT; K = 512; Nsrc = 1024; NB = 3072; noff = 2048; }
        else if (t < 2048) { t -= 1536; in = Wo; outp = WoT; K = 1024; Nsrc = 512; NB = 512; noff = 0; }
        else if (t < 3072) { t -= 2048; in = W1; outp = W1T; K = 512; Nsrc = 2048; NB = 2048; noff = 0; }
        else { t -= 3072; in = W2; outp = W2T; K = 2048; Nsrc = 512; NB = 512; noff = 0; }
        int tilesX = Nsrc >> 5;
        int bx = t % tilesX, by = t / tilesX;
        int x0 = bx * 32, y0 = by * 32;
        __shared__ float tile[32][33];
        int tx = tid & 31, ty = tid >> 5;  // 32 x 8
#pragma unroll
        for (int r = 0; r < 4; r++) {
            int y = y0 + ty + r * 8;       // k index
            tile[ty + r * 8][tx] = in[(size_t)y * Nsrc + x0 + tx];
        }
        __syncthreads();
#pragma unroll
        for (int r = 0; r < 4; r++) {
            int n = x0 + ty + r * 8;       // source col
            int k = y0 + tx;
            outp[(((size_t)(k >> 3) * NB + noff + n) << 3) + (k & 7)] = f2bf(tile[tx][ty + r * 8]);
        }
    } else if (blk < 8192) {
        // pack F[16384][512] -> Fb panels (reads contiguous, writes strided->L2)
        int gi = (blk - 4096) * 256 + tid;   // 16384*64 slots
        int row = gi >> 6, p = gi & 63;
        const float4* src = (const float4*)(F + (size_t)row * 512 + p * 8);
        float4 a = src[0], c = src[1];
        uint32_t w0 = f2bf(a.x) | ((uint32_t)f2bf(a.y) << 16);
        uint32_t w1 = f2bf(a.z) | ((uint32_t)f2bf(a.w) << 16);
        uint32_t w2 = f2bf(c.x) | ((uint32_t)f2bf(c.y) << 16);
        uint32_t w3 = f2bf(c.z) | ((uint32_t)f2bf(c.w) << 16);
        ((uint4*)Fb)[(size_t)p * 16384 + row] = make_uint4(w0, w1, w2, w3);
    } else if (blk < 8204) {
        int i = (blk - 8192) * 256 + tid;
        if (i < 1024) bqkv[i] = bq[i];
        else if (i < 2048) bqkv[i] = bk[i - 1024];
        else if (i < 3072) bqkv[i] = bv[i - 2048];
    } else {
        int wv = (blk - 8204) * 4 + (tid >> 6);
        int l = tid & 63;
        int b = wv >> 10, n = wv & 1023;
        const float* vb = verts + (size_t)b * 1024 * 3;
        float qx = vb[n * 3 + 0], qy = vb[n * 3 + 1], qz = vb[n * 3 + 2];
        float q2 = qx * qx + qy * qy + qz * qz;
        float d[16];
#pragma unroll
        for (int t = 0; t < 16; t++) {
            int p = l + 64 * t;
            float px = vb[p * 3 + 0], py = vb[p * 3 + 1], pz = vb[p * 3 + 2];
            float p2 = px * px + py * py + pz * pz;
            float dot = qx * px + qy * py + qz * pz;
            d[t] = q2 + p2 - 2.f * dot;
        }
        int* outp = nbr + (size_t)wv * 20;
        for (int it = 0; it < 20; it++) {
            float dm = d[0]; int im = 0;
#pragma unroll
            for (int t = 1; t < 16; t++) { if (d[t] < dm) { dm = d[t]; im = t; } }
            int g = im * 64 + l;
#pragma unroll
            for (int off = 32; off >= 1; off >>= 1) {
                float od = __shfl_xor(dm, off);
                int og = __shfl_xor(g, off);
                if (od < dm || (od == dm && og < g)) { dm = od; g = og; }
            }
            int wl = g & 63, wt = g >> 6;
            if (l == wl) {
#pragma unroll
                for (int t = 0; t < 16; t++) if (t == wt) d[t] = 3.4e38f;
            }
            if (l == 0) outp[it] = g;
        }
    }
}

// ---------------------------------------------------------------- GEMM ----
// C[M,N] = A[M,K] * B[K,N] with BOTH operands in packed panel layout
// (A panels stride MA=M rows, B panels stride NB=N rows). bf16 in, fp32
// accum, MFMA 16x16x32, BK=32, 128x128 tile. R7's register-staged
// ping-pong double buffer (verified correct) with COALESCED staging loads:
// wave reads 64 consecutive uint4 slots of one panel = 1KB contiguous.
// gridDim.z = split-K (partials). Column-major block remap for L2.
// EPI: 0 bias->bf16 row-major | 1 bias+relu->PACKED bf16 | 3 partial->fp32
template <int EPI>
__global__ __launch_bounds__(256) void gemm_bt(const u16* __restrict__ A,
                                               const u16* __restrict__ BT,
                                               const float* __restrict__ bias,
                                               u16* __restrict__ Cb,
                                               float* __restrict__ Cf,
                                               float* __restrict__ Cf2,
                                               int M, int N, int Klen,
                                               int MA, int NB, int Koff) {
    __shared__ __align__(16) u16 As0[4096], As1[4096];   // 8KB each: [kq][row][8]
    __shared__ __align__(16) u16 Bs0[4096], Bs1[4096];
    int tid = threadIdx.x;
    int id = blockIdx.y * gridDim.x + blockIdx.x;
    int by = id % gridDim.y, bx = id / gridDim.y;
    int m0 = by * 128, n0 = bx * 128;
    int kz = blockIdx.z;
    const uint4* A4 = (const uint4*)A + (size_t)kz * (Koff >> 3) * MA;
    const uint4* B4 = (const uint4*)BT + (size_t)kz * (Koff >> 3) * NB;
    int w = tid >> 6, l = tid & 63;
    int wr = w >> 1, wc = w & 1, quad = l >> 4, ln = l & 15;
    // staging: slot i=tid -> (panel q=tid>>7, row tid&127); i=tid+256 -> q+2
    int qA = tid >> 7, rA = tid & 127;
    const uint4* pA0 = A4 + (size_t)qA * MA + m0 + rA;
    const uint4* pA1 = pA0 + 2 * (size_t)MA;
    const uint4* pB0 = B4 + (size_t)qA * NB + n0 + rA;
    const uint4* pB1 = pB0 + 2 * (size_t)NB;

    f32x4 acc[4][4];
#pragma unroll
    for (int i = 0; i < 4; i++)
#pragma unroll
        for (int j = 0; j < 4; j++) acc[i][j] = (f32x4){0.f, 0.f, 0.f, 0.f};

    uint4 a00, a01, b00, b01;   // bank 0 (even tiles -> buf0)
    uint4 a10, a11, b10, b11;   // bank 1 (odd tiles  -> buf1)

#define ISSUE0(ko) do { size_t kq = (size_t)((ko) >> 3);                             \
        a00 = pA0[kq * MA]; a01 = pA1[kq * MA];                                      \
        b00 = pB0[kq * NB]; b01 = pB1[kq * NB]; } while (0)
#define ISSUE1(ko) do { size_t kq = (size_t)((ko) >> 3);                             \
        a10 = pA0[kq * MA]; a11 = pA1[kq * MA];                                      \
        b10 = pB0[kq * NB]; b11 = pB1[kq * NB]; } while (0)
#define WRITE0() do { *(uint4*)((char*)As0 + tid * 16) = a00; *(uint4*)((char*)As0 + (tid + 256) * 16) = a01; \
                      *(uint4*)((char*)Bs0 + tid * 16) = b00; *(uint4*)((char*)Bs0 + (tid + 256) * 16) = b01; } while (0)
#define WRITE1() do { *(uint4*)((char*)As1 + tid * 16) = a10; *(uint4*)((char*)As1 + (tid + 256) * 16) = a11; \
                      *(uint4*)((char*)Bs1 + tid * 16) = b10; *(uint4*)((char*)Bs1 + (tid + 256) * 16) = b11; } while (0)
#define COMPUTE(Asb, Bsb) do {                                                            \
        const bf16x8* Av = (const bf16x8*)(Asb);                                          \
        const bf16x8* Bv = (const bf16x8*)(Bsb);                                          \
        bf16x8 af[4], bfr[4];                                                             \
        _Pragma("unroll")                                                                 \
        for (int i = 0; i < 4; i++) af[i] = Av[quad * 128 + wr * 64 + i * 16 + ln];       \
        _Pragma("unroll")                                                                 \
        for (int j = 0; j < 4; j++) bfr[j] = Bv[quad * 128 + wc * 64 + j * 16 + ln];      \
        _Pragma("unroll")                                                                 \
        for (int i = 0; i < 4; i++)                                                       \
            _Pragma("unroll")                                                             \
            for (int j = 0; j < 4; j++)                                                   \
                acc[i][j] = __builtin_amdgcn_mfma_f32_16x16x32_bf16(af[i], bfr[j], acc[i][j], 0, 0, 0); \
    } while (0)
#define LGKM_BARRIER() do { asm volatile("s_waitcnt lgkmcnt(0)" ::: "memory"); \
                            __builtin_amdgcn_s_barrier(); } while (0)

    int nIter = Klen >> 5;   // even, >= 4 for all shapes used
    ISSUE0(0);
    ISSUE1(32);
    WRITE0();
    LGKM_BARRIER();
    for (int kt = 0; kt < nIter; kt += 2) {
        if (kt + 2 < nIter) ISSUE0((kt + 2) * 32);
        COMPUTE(As0, Bs0);                 // tile kt
        WRITE1();                          // tile kt+1 (bank1 loads ~1 body old)
        LGKM_BARRIER();
        if (kt + 3 < nIter) ISSUE1((kt + 3) * 32);
        COMPUTE(As1, Bs1);                 // tile kt+1
        if (kt + 2 < nIter) {
            WRITE0();                      // tile kt+2 (bank0 loads ~1 body old)
            LGKM_BARRIER();
        }
    }
#undef ISSUE0
#undef ISSUE1
#undef WRITE0
#undef WRITE1
#undef COMPUTE
#undef LGKM_BARRIER

    float* Cfz = (EPI == 3) ? (kz ? Cf2 : Cf) : Cf;
    // epilogue: row = m0+wr*64+i*16+quad*4+r, col = n0+wc*64+j*16+ln
#pragma unroll
    for (int i = 0; i < 4; i++) {
        int row_base = m0 + wr * 64 + i * 16 + quad * 4;
#pragma unroll
        for (int j = 0; j < 4; j++) {
            int col = n0 + wc * 64 + j * 16 + ln;
            float bb = (EPI == 3) ? 0.f : bias[col];
#pragma unroll
            for (int r = 0; r < 4; r++) {
                int row = row_base + r;
                float v = acc[i][j][r] + bb;
                if (EPI == 0) Cb[(size_t)row * N + col] = f2bf(v);
                else if (EPI == 1)  // packed output (next GEMM's A operand)
                    Cb[(((size_t)(col >> 3) * M + row) << 3) + (col & 7)] = f2bf(v > 0.f ? v : 0.f);
                else Cfz[(size_t)row * N + col] = v;
            }
        }
    }
}

// ----------------------------------------------------- sparse attention ----
__global__ __launch_bounds__(256) void attn_kernel(const u16* __restrict__ QKV,
                                                   const int* __restrict__ nbr,
                                                   u16* __restrict__ outA) {
    int tid = threadIdx.x;
    int wv = blockIdx.x * 4 + (tid >> 6);  // b*1024+n
    int l = tid & 63;
    int h = l >> 4, sx = l & 15;
    int bbase = (wv >> 10) << 10;

    int nv = 0;
    if (l < 20) nv = nbr[(size_t)wv * 20 + l];

    const uint32_t* qp = (const uint32_t*)(QKV + (size_t)wv * 3072 + h * 256 + sx * 16);
    uint32_t qw[8];
    *(uint4*)(qw) = *(const uint4*)qp;
    *(uint4*)(qw + 4) = *(const uint4*)(qp + 4);
    float qf[16];
#pragma unroll
    for (int i = 0; i < 8; i++) { qf[2 * i] = bfbits_lo(qw[i]); qf[2 * i + 1] = bfbits_hi(qw[i]); }

    float wj[20];
#pragma unroll
    for (int j = 0; j < 20; j++) {
        int m = __shfl(nv, j);
        const uint32_t* kp = (const uint32_t*)(QKV + (size_t)(bbase + m) * 3072 + 1024 + h * 256 + sx * 16);
        uint32_t kw[8];
        *(uint4*)(kw) = *(const uint4*)kp;
        *(uint4*)(kw + 4) = *(const uint4*)(kp + 4);
        float acc = 0.f;
#pragma unroll
        for (int i = 0; i < 8; i++) {
            acc += qf[2 * i] * bfbits_lo(kw[i]);
            acc += qf[2 * i + 1] * bfbits_hi(kw[i]);
        }
#pragma unroll
        for (int off = 1; off < 16; off <<= 1) acc += __shfl_xor(acc, off);
        wj[j] = acc * 0.0625f;
    }
    float mx = wj[0];
#pragma unroll
    for (int j = 1; j < 20; j++) mx = fmaxf(mx, wj[j]);
    float ssum = 0.f;
#pragma unroll
    for (int j = 0; j < 20; j++) { wj[j] = __expf(wj[j] - mx); ssum += wj[j]; }
    float inv = 1.f / ssum;

    float o[16];
#pragma unroll
    for (int i = 0; i < 16; i++) o[i] = 0.f;
#pragma unroll
    for (int j = 0; j < 20; j++) {
        int m = __shfl(nv, j);
        const uint32_t* vp = (const uint32_t*)(QKV + (size_t)(bbase + m) * 3072 + 2048 + h * 256 + sx * 16);
        uint32_t vw[8];
        *(uint4*)(vw) = *(const uint4*)vp;
        *(uint4*)(vw + 4) = *(const uint4*)(vp + 4);
        float ww = wj[j] * inv;
#pragma unroll
        for (int i = 0; i < 8; i++) {
            o[2 * i] += ww * bfbits_lo(vw[i]);
            o[2 * i + 1] += ww * bfbits_hi(vw[i]);
        }
    }
    uint32_t ow[8];
#pragma unroll
    for (int i = 0; i < 8; i++) ow[i] = f2bf(o[2 * i]) | ((uint32_t)f2bf(o[2 * i + 1]) << 16);
    // packed store: cols h*256+sx*16 .. +15 -> panels h*32+sx*2, h*32+sx*2+1, row wv
    size_t slot = (size_t)(h * 32 + sx * 2) * 16384 + wv;
    ((uint4*)outA)[slot] = make_uint4(ow[0], ow[1], ow[2], ow[3]);
    ((uint4*)outA)[slot + 16384] = make_uint4(ow[4], ow[5], ow[6], ow[7]);
}

// ------------------------------------------------- LN over split-K sum ----
// LN(P0 + P1 + res + biasv) -> Yf fp32 (+ Yb PACKED bf16 if WB)
template <int WB>
__global__ __launch_bounds__(256) void ln12p_kernel(const float* __restrict__ P0,
                                                    const float* __restrict__ P1,
                                                    const float* __restrict__ res,
                                                    const float* __restrict__ biasv,
                                                    const float* __restrict__ g,
                                                    const float* __restrict__ bparm,
                                                    float* __restrict__ Yf,
                                                    u16* __restrict__ Yb) {
    int tid = threadIdx.x;
    int row = blockIdx.x * 4 + (tid >> 6);
    int l = tid & 63;
    size_t base = (size_t)row * 512;
    const float4* p0 = (const float4*)(P0 + base) + l * 2;
    const float4* p1 = (const float4*)(P1 + base) + l * 2;
    const float4* rr = (const float4*)(res + base) + l * 2;
    const float4* bv = (const float4*)biasv + l * 2;
    float xs[8];
#pragma unroll
    for (int h = 0; h < 2; h++) {
        float4 a = p0[h], b = p1[h], c = rr[h], d = bv[h];
        xs[4 * h + 0] = a.x + b.x + c.x + d.x;
        xs[4 * h + 1] = a.y + b.y + c.y + d.y;
        xs[4 * h + 2] = a.z + b.z + c.z + d.z;
        xs[4 * h + 3] = a.w + b.w + c.w + d.w;
    }
    float s = 0.f;
#pragma unroll
    for (int i = 0; i < 8; i++) s += xs[i];
#pragma unroll
    for (int off = 32; off >= 1; off >>= 1) s += __shfl_xor(s, off);
    float mu = s * (1.f / 512.f);
    float q = 0.f;
#pragma unroll
    for (int i = 0; i < 8; i++) { float dd = xs[i] - mu; q += dd * dd; }
#pragma unroll
    for (int off = 32; off >= 1; off >>= 1) q += __shfl_xor(q, off);
    float var = q * (1.f / 512.f);
    float rs = rsqrtf(var + 1e-5f);
    const float4* gp = (const float4*)g + l * 2;
    const float4* bp = (const float4*)bparm + l * 2;
    float4 g0 = gp[0], g1 = gp[1], b0 = bp[0], b1 = bp[1];
    float gg[8] = {g0.x, g0.y, g0.z, g0.w, g1.x, g1.y, g1.z, g1.w};
    float bbv[8] = {b0.x, b0.y, b0.z, b0.w, b1.x, b1.y, b1.z, b1.w};
    float y[8];
#pragma unroll
    for (int i = 0; i < 8; i++) y[i] = (xs[i] - mu) * rs * gg[i] + bbv[i];
    float4* yo = (float4*)(Yf + base) + l * 2;
    yo[0] = make_float4(y[0], y[1], y[2], y[3]);
    yo[1] = make_float4(y[4], y[5], y[6], y[7]);
    if (WB) {
        uint32_t w0 = f2bf(y[0]) | ((uint32_t)f2bf(y[1]) << 16);
        uint32_t w1 = f2bf(y[2]) | ((uint32_t)f2bf(y[3]) << 16);
        uint32_t w2 = f2bf(y[4]) | ((uint32_t)f2bf(y[5]) << 16);
        uint32_t w3 = f2bf(y[6]) | ((uint32_t)f2bf(y[7]) << 16);
        // packed: lane l holds k = l*8..l*8+7 of this row -> panel l
        ((uint4*)Yb)[(size_t)l * 16384 + row] = make_uint4(w0, w1, w2, w3);
    }
}

// ------------------------------------------------------------ launcher ----
extern "C" void kernel_launch(void* const* d_in, const int* in_sizes, int n_in,
                              void* d_out, int out_size, void* d_ws, size_t ws_size,
                              hipStream_t stream) {
    const float* verts = (const float*)d_in[0];
    const float* F = (const float*)d_in[1];
    const float* Wq = (const float*)d_in[2];
    const float* bq = (const float*)d_in[3];
    const float* Wk = (const float*)d_in[4];
    const float* bk = (const float*)d_in[5];
    const float* Wv = (const float*)d_in[6];
    const float* bv = (const float*)d_in[7];
    const float* Wo = (const float*)d_in[8];
    const float* bo = (const float*)d_in[9];
    const float* ln1g = (const float*)d_in[10];
    const float* ln1b = (const float*)d_in[11];
    const float* W1 = (const float*)d_in[12];
    const float* b1 = (const float*)d_in[13];
    const float* W2 = (const float*)d_in[14];
    const float* b2 = (const float*)d_in[15];
    const float* ln2g = (const float*)d_in[16];
    const float* ln2b = (const float*)d_in[17];
    float* out = (float*)d_out;

    char* ws = (char*)d_ws;
    // arena (lifetime-overlapped), ~177.5 MB:
    u16* QKV = (u16*)(ws);                         // [0, 96MB)  G1 -> attn (row-major)
    float* Q0 = (float*)(ws);                      // [0, 32MB)  G2 partial 0 -> LN1
    float* Q1 = (float*)(ws + 33554432);           // [32, 64MB) G2 partial 1 -> LN1
    u16* Hb = (u16*)(ws);                          // [0, 64MB)  G3 -> G4 (packed)
    float* P1 = (float*)(ws + 67108864);           // [64, 96MB) G4 partial 1 -> LN2
    u16* ATT = (u16*)(ws + 100663296);             // [96, 128MB) attn -> G2 (packed)
    u16* xb = ATT;                                 //   reuse: LN1 -> G3 (packed)
    float* P0 = (float*)(ws + 100663296);          //   reuse: G4 partial 0 -> LN2
    u16* Fb = (u16*)(ws + 134217728);              // [128, 144.8MB) prep -> G1 (packed)
    float* X32 = (float*)(ws + 134217728);         //   reuse: LN1 -> LN2 (33.5MB)
    char* wsw = ws + 167772160;
    u16* WqkvT = (u16*)(wsw);                      // 3,145,728 (packed)
    u16* WoT = (u16*)(wsw + 3145728);              // 1,048,576 (packed)
    u16* W1T = (u16*)(wsw + 4194304);              // 2,097,152 (packed)
    u16* W2T = (u16*)(wsw + 6291456);              // 2,097,152 (packed)
    float* bqkv = (float*)(wsw + 8388608);         // 16,384 (padded)
    int* nbr = (int*)(wsw + 8404992);              // 1,310,720

    // PREP (one dispatch): transposes+pack + F pack + bias + KNN
    prep_kernel<<<12300, 256, 0, stream>>>(verts, F, Wq, Wk, Wv, Wo, W1, W2,
                                           bq, bk, bv, WqkvT, WoT, W1T, W2T,
                                           bqkv, Fb, nbr);
    // G1: QKV = Fb @ Wqkv + bias -> bf16 row-major [16384, 3072]
    gemm_bt<0><<<dim3(24, 128, 1), 256, 0, stream>>>(Fb, WqkvT, bqkv, QKV, nullptr, nullptr,
                                                     16384, 3072, 512, 16384, 3072, 0);
    // sparse attention -> ATT packed [16384, 1024]
    attn_kernel<<<4096, 256, 0, stream>>>(QKV, nbr, ATT);
    // G2 split-K x2: Q0/Q1 = ATT @ Wo (partials) [16384, 512]
    gemm_bt<3><<<dim3(4, 128, 2), 256, 0, stream>>>(ATT, WoT, nullptr, nullptr, Q0, Q1,
                                                    16384, 512, 512, 16384, 512, 512);
    // LN1: LN(Q0+Q1+bo+F) -> X32 fp32 + xb packed bf16
    ln12p_kernel<1><<<4096, 256, 0, stream>>>(Q0, Q1, F, bo, ln1g, ln1b, X32, xb);
    // G3: Hb = relu(xb @ W1 + b1) -> packed bf16 [16384, 2048]
    gemm_bt<1><<<dim3(16, 128, 1), 256, 0, stream>>>(xb, W1T, b1, Hb, nullptr, nullptr,
                                                     16384, 2048, 512, 16384, 2048, 0);
    // G4 split-K x2: P0/P1 = Hb @ W2 (partials) [16384, 512]
    gemm_bt<3><<<dim3(4, 128, 2), 256, 0, stream>>>(Hb, W2T, nullptr, nullptr, P0, P1,
                                                    16384, 512, 1024, 16384, 512, 1024);
    // LN2: LN(P0+P1+b2+X32) -> out
    ln12p_kernel<0><<<4096, 256, 0, stream>>>(P0, P1, X32, b2, ln2g, ln2b, out, nullptr);
}